// Round 3
// baseline (681.866 us; speedup 1.0000x reference)
//
#include <hip/hip_runtime.h>
#include <hip/hip_bf16.h>
#include <math.h>

#define BATCH 65536
#define NODES 1024
#define ZD    256
#define KS    768   // split-K: [hi|hi|lo] x [hi|lo|hi]
#define EPSGAP 0.01f

// d_out layout (floats): z_e, k, z_q, nw, dist
#define OFF_ZE   0ull
#define OFF_K    16777216ull
#define OFF_ZQ   16842752ull
#define OFF_NW   33619968ull
#define OFF_DIST 100728832ull

typedef __attribute__((ext_vector_type(8))) short short8v;
typedef __attribute__((ext_vector_type(4))) float f32x4;

#define GLOAD16(g, l) __builtin_amdgcn_global_load_lds( \
    (const __attribute__((address_space(1))) void*)(g), \
    (__attribute__((address_space(3))) void*)(l), 16, 0, 0)

__device__ inline float wave_reduce_add(float s) {
#pragma unroll
    for (int off = 32; off; off >>= 1) s += __shfl_down(s, off);
    return s;
}

// ---------------- split f32 -> (hi,lo) bf16 segments + row norms ----------------
__global__ __launch_bounds__(256) void split_k(const float* __restrict__ X,
                                               ushort* __restrict__ P,
                                               float* __restrict__ norms,
                                               int isA) {
    int row  = blockIdx.x * 4 + (threadIdx.x >> 6);
    int lane = threadIdx.x & 63;
    float4 v = ((const float4*)(X + (size_t)row * ZD))[lane];
    float s = v.x * v.x + v.y * v.y + v.z * v.z + v.w * v.w;
    s = wave_reduce_add(s);
    if (lane == 0) norms[row] = s;

    float xs[4] = {v.x, v.y, v.z, v.w};
    ushort hi[4], lo[4];
#pragma unroll
    for (int i = 0; i < 4; ++i) {
        __hip_bfloat16 h = __float2bfloat16(xs[i]);
        float hf = __bfloat162float(h);
        __hip_bfloat16 l = __float2bfloat16(xs[i] - hf);
        hi[i] = *(ushort*)&h;
        lo[i] = *(ushort*)&l;
    }
    ushort4 h4 = make_ushort4(hi[0], hi[1], hi[2], hi[3]);
    ushort4 l4 = make_ushort4(lo[0], lo[1], lo[2], lo[3]);
    ushort* base = P + (size_t)row * KS + lane * 4;
    *(ushort4*)(base) = h4;
    if (isA) { *(ushort4*)(base + 256) = h4; *(ushort4*)(base + 512) = l4; }
    else     { *(ushort4*)(base + 256) = l4; *(ushort4*)(base + 512) = h4; }
}

// ---------------- MFMA dist GEMM + fused per-block top-2 ----------------
__global__ __launch_bounds__(256) void dist_mfma_k(const ushort* __restrict__ Ap,
                                                   const ushort* __restrict__ Bp,
                                                   const float* __restrict__ xn,
                                                   const float* __restrict__ yn,
                                                   float* __restrict__ D,
                                                   float4* __restrict__ partials) {
    __shared__ ushort As[2][128 * 64];
    __shared__ ushort Bs[2][128 * 64];

    const int tid  = threadIdx.x;
    const int lane = tid & 63;
    const int wave = tid >> 6;
    const int wr = wave >> 1, wc = wave & 1;

    int orig = blockIdx.x;
    int wg = (orig & 7) * 512 + (orig >> 3);   // 4096 % 8 == 0 -> bijective
    const int bm = wg >> 3, bn = wg & 7;

    f32x4 acc[4][4];
#pragma unroll
    for (int i = 0; i < 4; ++i)
#pragma unroll
        for (int j = 0; j < 4; ++j) acc[i][j] = f32x4{0.f, 0.f, 0.f, 0.f};

    const int sg    = tid & 7;
    const int srow0 = tid >> 3;

    auto stage = [&](int buf, int kstep) {
#pragma unroll
        for (int i = 0; i < 4; ++i) {
            int row = i * 32 + srow0;
            int ss = sg ^ (row & 7);
            const ushort* ga = Ap + (size_t)(bm * 128 + row) * KS + kstep * 64 + ss * 8;
            GLOAD16(ga, &As[buf][(row * 8 + sg) * 8]);
            const ushort* gb = Bp + (size_t)(bn * 128 + row) * KS + kstep * 64 + ss * 8;
            GLOAD16(gb, &Bs[buf][(row * 8 + sg) * 8]);
        }
    };

    const int frow = lane & 15;
    const int fk   = lane >> 4;
    int a_off[4], a_x7[4], b_off[4], b_x7[4];
#pragma unroll
    for (int f = 0; f < 4; ++f) {
        int ar = wr * 64 + f * 16 + frow;
        a_off[f] = ar * 64;  a_x7[f] = ar & 7;
        int br = wc * 64 + f * 16 + frow;
        b_off[f] = br * 64;  b_x7[f] = br & 7;
    }

    auto compute = [&](int buf) {
#pragma unroll
        for (int k32 = 0; k32 < 2; ++k32) {
            int skb = k32 * 4 + fk;
            short8v af[4], bf[4];
#pragma unroll
            for (int f = 0; f < 4; ++f)
                af[f] = *(const short8v*)&As[buf][a_off[f] + ((skb ^ a_x7[f]) * 8)];
#pragma unroll
            for (int f = 0; f < 4; ++f)
                bf[f] = *(const short8v*)&Bs[buf][b_off[f] + ((skb ^ b_x7[f]) * 8)];
#pragma unroll
            for (int i = 0; i < 4; ++i)
#pragma unroll
                for (int j = 0; j < 4; ++j)
                    acc[i][j] = __builtin_amdgcn_mfma_f32_16x16x32_bf16(af[i], bf[j], acc[i][j], 0, 0, 0);
        }
    };

    stage(0, 0);
    __syncthreads();
    for (int ks = 0; ks < 12; ++ks) {
        int cur = ks & 1;
        if (ks + 1 < 12) stage(cur ^ 1, ks + 1);
        compute(cur);
        __syncthreads();
    }

    // ---- epilogue: d = max(xn+yn-2*acc,0), write dist, fused top-2 ----
    float yv[4];
    const int cb0 = bn * 128 + wc * 64 + frow;
#pragma unroll
    for (int fn = 0; fn < 4; ++fn) yv[fn] = yn[cb0 + fn * 16];

    float4* red = (float4*)&As[0][0];   // [128][2] of (v1,c1,v2,c2)

#pragma unroll
    for (int fm = 0; fm < 4; ++fm) {
        const int rl0 = wr * 64 + fm * 16 + fk * 4;
#pragma unroll
        for (int j = 0; j < 4; ++j) {
            int rloc = rl0 + j;
            size_t grow = (size_t)(bm * 128 + rloc);
            float xv = xn[grow];
            float* drow = D + grow * NODES;
            float v1 = 3.4e38f, v2 = 3.4e38f;
            int   c1 = 1 << 30,  c2 = 1 << 30;
#pragma unroll
            for (int fn = 0; fn < 4; ++fn) {
                float d = fmaxf(xv + yv[fn] - 2.0f * acc[fm][fn][j], 0.0f);
                int c = cb0 + fn * 16;
                drow[c] = d;
                if (d < v1 || (d == v1 && c < c1)) { v2 = v1; c2 = c1; v1 = d; c1 = c; }
                else if (d < v2 || (d == v2 && c < c2)) { v2 = d; c2 = c; }
            }
#pragma unroll
            for (int off = 1; off < 16; off <<= 1) {
                float w1 = __shfl_xor(v1, off); int d1 = __shfl_xor(c1, off);
                float w2 = __shfl_xor(v2, off); int d2 = __shfl_xor(c2, off);
                if (w1 < v1 || (w1 == v1 && d1 < c1)) { v2 = v1; c2 = c1; v1 = w1; c1 = d1; }
                else if (w1 < v2 || (w1 == v2 && d1 < c2)) { v2 = w1; c2 = d1; }
                if (w2 < v2 || (w2 == v2 && d2 < c2)) {
                    if (w2 < v1 || (w2 == v1 && d2 < c1)) { v2 = v1; c2 = c1; v1 = w2; c1 = d2; }
                    else { v2 = w2; c2 = d2; }
                }
            }
            if (frow == 0) red[rloc * 2 + wc] = make_float4(v1, (float)c1, v2, (float)c2);
        }
    }
    __syncthreads();
    if (tid < 128) {
        float4 a = red[tid * 2 + 0];
        float4 b = red[tid * 2 + 1];
        float v1 = a.x, c1 = a.y, v2 = a.z, c2 = a.w;
        if (b.x < v1 || (b.x == v1 && b.y < c1)) { v2 = v1; c2 = c1; v1 = b.x; c1 = b.y; }
        else if (b.x < v2 || (b.x == v2 && b.y < c2)) { v2 = b.x; c2 = b.y; }
        if (b.z < v2 || (b.z == v2 && b.w < c2)) {
            if (b.z < v1 || (b.z == v1 && b.w < c1)) { v2 = v1; c2 = c1; v1 = b.z; c1 = b.w; }
            else { v2 = b.z; c2 = b.w; }
        }
        partials[(size_t)(bm * 128 + tid) * 8 + bn] = make_float4(v1, c1, v2, c2);
    }
}

// ---------------- merge 8 block top-2s -> k, list ambiguous rows ----------------
__global__ __launch_bounds__(256) void finish1_k(const float4* __restrict__ partials,
                                                 float* __restrict__ out_k,
                                                 int* __restrict__ refine_cnt,
                                                 int* __restrict__ refine_list) {
    int r = blockIdx.x * 256 + threadIdx.x;
    float v1 = 3.4e38f, c1 = 2.0e9f, v2 = 3.4e38f, c2 = 2.0e9f;
#pragma unroll
    for (int i = 0; i < 8; ++i) {
        float4 p = partials[(size_t)r * 8 + i];
        if (p.x < v1 || (p.x == v1 && p.y < c1)) { v2 = v1; c2 = c1; v1 = p.x; c1 = p.y; }
        else if (p.x < v2 || (p.x == v2 && p.y < c2)) { v2 = p.x; c2 = p.y; }
        if (p.z < v2 || (p.z == v2 && p.w < c2)) {
            if (p.z < v1 || (p.z == v1 && p.w < c1)) { v2 = v1; c2 = c1; v1 = p.z; c1 = p.w; }
            else { v2 = p.z; c2 = p.w; }
        }
    }
    out_k[r] = c1;
    if (v2 - v1 < EPSGAP) {
        int slot = atomicAdd(refine_cnt, 1);
        refine_list[slot] = r;
    }
}

__global__ void zero_k(int* p) { *p = 0; }

// ---------------- exact f32 re-argmin for near-tie rows ----------------
__global__ __launch_bounds__(256) void refine_k(const float* __restrict__ ze,
                                                const float* __restrict__ cb,
                                                const float* __restrict__ xn,
                                                const float* __restrict__ yn,
                                                const int* __restrict__ refine_cnt,
                                                const int* __restrict__ refine_list,
                                                float* __restrict__ out_k) {
    __shared__ float zs[ZD];
    __shared__ float rv[4];
    __shared__ int   rc[4];
    int n = *refine_cnt;
    for (int idx = blockIdx.x; idx < n; idx += gridDim.x) {
        int r = refine_list[idx];
        __syncthreads();
        zs[threadIdx.x] = ze[(size_t)r * ZD + threadIdx.x];
        __syncthreads();
        float xv = xn[r];
        float bv = 3.4e38f; int bc = 1 << 30;
#pragma unroll
        for (int m = 0; m < 4; ++m) {
            int j = threadIdx.x + m * 256;
            const float* crow = cb + (size_t)j * ZD;
            float dot = 0.0f;
            for (int k = 0; k < ZD; ++k) dot = fmaf(zs[k], crow[k], dot);
            float d = fmaxf((xv + yn[j]) - 2.0f * dot, 0.0f);
            if (d < bv) { bv = d; bc = j; }   // j ascending per thread
        }
#pragma unroll
        for (int off = 32; off; off >>= 1) {
            float ov = __shfl_down(bv, off);
            int   oc = __shfl_down(bc, off);
            if (ov < bv || (ov == bv && oc < bc)) { bv = ov; bc = oc; }
        }
        int lane = threadIdx.x & 63, w = threadIdx.x >> 6;
        if (lane == 0) { rv[w] = bv; rc[w] = bc; }
        __syncthreads();
        if (threadIdx.x == 0) {
            float fv = rv[0]; int fc = rc[0];
#pragma unroll
            for (int i = 1; i < 4; ++i)
                if (rv[i] < fv || (rv[i] == fv && rc[i] < fc)) { fv = rv[i]; fc = rc[i]; }
            out_k[r] = (float)fc;
        }
    }
}

// ---------------- z_e copy + z_q gather + neighbour weights ----------------
__global__ __launch_bounds__(256) void finish2_k(const float* __restrict__ ze,
                                                 const float* __restrict__ cb,
                                                 const int* __restrict__ epoch_p,
                                                 const float* __restrict__ kf,
                                                 float* __restrict__ out_ze,
                                                 float* __restrict__ out_zq,
                                                 float* __restrict__ out_nw) {
    int row  = blockIdx.x * 4 + (threadIdx.x >> 6);
    int lane = threadIdx.x & 63;

    int ep = epoch_p[0];
    double sig = 16.0 * exp((double)ep * -0.034657359027997265);
    float ninv = (float)(-1.0 / (2.0 * sig * sig));

    int k = (int)kf[row];

    const float4* cbp = (const float4*)(cb + (size_t)k * ZD);
    const float4* zep = (const float4*)(ze + (size_t)row * ZD);
    ((float4*)(out_zq + (size_t)row * ZD))[lane] = cbp[lane];
    ((float4*)(out_ze + (size_t)row * ZD))[lane] = zep[lane];

    int kx = k >> 5, ky = k & 31;
    float4* nwp = (float4*)(out_nw + (size_t)row * NODES);
#pragma unroll
    for (int i = 0; i < 4; ++i) {
        int q = i * 64 + lane;
        int n = q * 4;
        float4 w;
        { int dx = ((n + 0) >> 5) - ky, dy = ((n + 0) & 31) - kx; w.x = __expf((float)(dx * dx + dy * dy) * ninv); }
        { int dx = ((n + 1) >> 5) - ky, dy = ((n + 1) & 31) - kx; w.y = __expf((float)(dx * dx + dy * dy) * ninv); }
        { int dx = ((n + 2) >> 5) - ky, dy = ((n + 2) & 31) - kx; w.z = __expf((float)(dx * dx + dy * dy) * ninv); }
        { int dx = ((n + 3) >> 5) - ky, dy = ((n + 3) & 31) - kx; w.w = __expf((float)(dx * dx + dy * dy) * ninv); }
        nwp[q] = w;
    }
}

extern "C" void kernel_launch(void* const* d_in, const int* in_sizes, int n_in,
                              void* d_out, int out_size, void* d_ws, size_t ws_size,
                              hipStream_t stream) {
    const float* z_e      = (const float*)d_in[0];
    const float* codebook = (const float*)d_in[1];
    const int*   epoch_p  = (const int*)d_in[2];
    float* out = (float*)d_out;

    // scratch in d_out regions that are overwritten later (all stream-ordered):
    //  nw region: Ap, Bp, xn, yn       (finish2 writes nw last)
    //  z_e region: partials            (finish2 writes z_e last)
    //  z_q region: refine count + list (finish2 writes z_q last)
    float* nwreg = out + OFF_NW;
    ushort* Ap = (ushort*)nwreg;                       // [65536][768] bf16
    ushort* Bp = Ap + (size_t)BATCH * KS;              // [1024][768]
    float*  xn = (float*)(Bp + (size_t)NODES * KS);    // [65536]
    float*  yn = xn + BATCH;                           // [1024]
    float4* partials = (float4*)(out + OFF_ZE);        // [65536][8]
    int* refine_cnt  = (int*)(out + OFF_ZQ);           // [1]
    int* refine_list = refine_cnt + 1;                 // [65536]

    zero_k<<<1, 1, 0, stream>>>(refine_cnt);
    split_k<<<BATCH / 4, 256, 0, stream>>>(z_e, Ap, xn, 1);
    split_k<<<NODES / 4, 256, 0, stream>>>(codebook, Bp, yn, 0);

    dist_mfma_k<<<4096, 256, 0, stream>>>(Ap, Bp, xn, yn, out + OFF_DIST, partials);

    finish1_k<<<BATCH / 256, 256, 0, stream>>>(partials, out + OFF_K, refine_cnt, refine_list);
    refine_k<<<256, 256, 0, stream>>>(z_e, codebook, xn, yn, refine_cnt, refine_list, out + OFF_K);
    finish2_k<<<BATCH / 4, 256, 0, stream>>>(z_e, codebook, epoch_p, out + OFF_K,
                                             out + OFF_ZE, out + OFF_ZQ, out + OFF_NW);
}

// Round 4
// 476.213 us; speedup vs baseline: 1.4319x; 1.4319x over previous
//
#include <hip/hip_runtime.h>
#include <hip/hip_bf16.h>
#include <math.h>

#define BATCH 65536
#define NODES 1024
#define ZD    256
#define KS    768   // split-K: [hi|hi|lo] x [hi|lo|hi]
#define EPSGAP 1.5e-3f
#define RB    8     // refine rows per block batch

// d_out layout (floats): z_e, k, z_q, nw, dist
#define OFF_ZE   0ull
#define OFF_K    16777216ull
#define OFF_ZQ   16842752ull
#define OFF_NW   33619968ull
#define OFF_DIST 100728832ull

typedef __attribute__((ext_vector_type(8))) short short8v;
typedef __attribute__((ext_vector_type(4))) float f32x4;

#define GLOAD16(g, l) __builtin_amdgcn_global_load_lds( \
    (const __attribute__((address_space(1))) void*)(g), \
    (__attribute__((address_space(3))) void*)(l), 16, 0, 0)

__device__ inline float wave_reduce_add(float s) {
#pragma unroll
    for (int off = 32; off; off >>= 1) s += __shfl_down(s, off);
    return s;
}

// ---------------- split f32 -> (hi,lo) bf16 segments + row norms ----------------
__global__ __launch_bounds__(256) void split_k(const float* __restrict__ X,
                                               ushort* __restrict__ P,
                                               float* __restrict__ norms,
                                               int isA) {
    int row  = blockIdx.x * 4 + (threadIdx.x >> 6);
    int lane = threadIdx.x & 63;
    float4 v = ((const float4*)(X + (size_t)row * ZD))[lane];
    float s = v.x * v.x + v.y * v.y + v.z * v.z + v.w * v.w;
    s = wave_reduce_add(s);
    if (lane == 0) norms[row] = s;

    float xs[4] = {v.x, v.y, v.z, v.w};
    ushort hi[4], lo[4];
#pragma unroll
    for (int i = 0; i < 4; ++i) {
        __hip_bfloat16 h = __float2bfloat16(xs[i]);
        float hf = __bfloat162float(h);
        __hip_bfloat16 l = __float2bfloat16(xs[i] - hf);
        hi[i] = *(ushort*)&h;
        lo[i] = *(ushort*)&l;
    }
    ushort4 h4 = make_ushort4(hi[0], hi[1], hi[2], hi[3]);
    ushort4 l4 = make_ushort4(lo[0], lo[1], lo[2], lo[3]);
    ushort* base = P + (size_t)row * KS + lane * 4;
    *(ushort4*)(base) = h4;
    if (isA) { *(ushort4*)(base + 256) = h4; *(ushort4*)(base + 512) = l4; }
    else     { *(ushort4*)(base + 256) = l4; *(ushort4*)(base + 512) = h4; }
}

// ---------------- MFMA dist GEMM + fused per-block top-2 ----------------
__global__ __launch_bounds__(256) void dist_mfma_k(const ushort* __restrict__ Ap,
                                                   const ushort* __restrict__ Bp,
                                                   const float* __restrict__ xn,
                                                   const float* __restrict__ yn,
                                                   float* __restrict__ D,
                                                   float4* __restrict__ partials) {
    __shared__ ushort As[2][128 * 64];
    __shared__ ushort Bs[2][128 * 64];

    const int tid  = threadIdx.x;
    const int lane = tid & 63;
    const int wave = tid >> 6;
    const int wr = wave >> 1, wc = wave & 1;

    int orig = blockIdx.x;
    int wg = (orig & 7) * 512 + (orig >> 3);   // 4096 % 8 == 0 -> bijective
    const int bm = wg >> 3, bn = wg & 7;

    f32x4 acc[4][4];
#pragma unroll
    for (int i = 0; i < 4; ++i)
#pragma unroll
        for (int j = 0; j < 4; ++j) acc[i][j] = f32x4{0.f, 0.f, 0.f, 0.f};

    const int sg    = tid & 7;
    const int srow0 = tid >> 3;

    auto stage = [&](int buf, int kstep) {
#pragma unroll
        for (int i = 0; i < 4; ++i) {
            int row = i * 32 + srow0;
            int ss = sg ^ (row & 7);
            const ushort* ga = Ap + (size_t)(bm * 128 + row) * KS + kstep * 64 + ss * 8;
            GLOAD16(ga, &As[buf][(row * 8 + sg) * 8]);
            const ushort* gb = Bp + (size_t)(bn * 128 + row) * KS + kstep * 64 + ss * 8;
            GLOAD16(gb, &Bs[buf][(row * 8 + sg) * 8]);
        }
    };

    const int frow = lane & 15;
    const int fk   = lane >> 4;
    int a_off[4], a_x7[4], b_off[4], b_x7[4];
#pragma unroll
    for (int f = 0; f < 4; ++f) {
        int ar = wr * 64 + f * 16 + frow;
        a_off[f] = ar * 64;  a_x7[f] = ar & 7;
        int br = wc * 64 + f * 16 + frow;
        b_off[f] = br * 64;  b_x7[f] = br & 7;
    }

    auto compute = [&](int buf) {
#pragma unroll
        for (int k32 = 0; k32 < 2; ++k32) {
            int skb = k32 * 4 + fk;
            short8v af[4], bf[4];
#pragma unroll
            for (int f = 0; f < 4; ++f)
                af[f] = *(const short8v*)&As[buf][a_off[f] + ((skb ^ a_x7[f]) * 8)];
#pragma unroll
            for (int f = 0; f < 4; ++f)
                bf[f] = *(const short8v*)&Bs[buf][b_off[f] + ((skb ^ b_x7[f]) * 8)];
#pragma unroll
            for (int i = 0; i < 4; ++i)
#pragma unroll
                for (int j = 0; j < 4; ++j)
                    acc[i][j] = __builtin_amdgcn_mfma_f32_16x16x32_bf16(af[i], bf[j], acc[i][j], 0, 0, 0);
        }
    };

    stage(0, 0);
    __syncthreads();
    for (int ks = 0; ks < 12; ++ks) {
        int cur = ks & 1;
        if (ks + 1 < 12) stage(cur ^ 1, ks + 1);
        compute(cur);
        __syncthreads();
    }

    // ---- epilogue: d = max(xn+yn-2*acc,0), write dist, fused top-2 ----
    float yv[4];
    const int cb0 = bn * 128 + wc * 64 + frow;
#pragma unroll
    for (int fn = 0; fn < 4; ++fn) yv[fn] = yn[cb0 + fn * 16];

    float4* red = (float4*)&As[0][0];   // [128][2] of (v1,c1,v2,c2)

#pragma unroll
    for (int fm = 0; fm < 4; ++fm) {
        const int rl0 = wr * 64 + fm * 16 + fk * 4;
#pragma unroll
        for (int j = 0; j < 4; ++j) {
            int rloc = rl0 + j;
            size_t grow = (size_t)(bm * 128 + rloc);
            float xv = xn[grow];
            float* drow = D + grow * NODES;
            float v1 = 3.4e38f, v2 = 3.4e38f;
            int   c1 = 1 << 30,  c2 = 1 << 30;
#pragma unroll
            for (int fn = 0; fn < 4; ++fn) {
                float d = fmaxf(xv + yv[fn] - 2.0f * acc[fm][fn][j], 0.0f);
                int c = cb0 + fn * 16;
                drow[c] = d;
                if (d < v1 || (d == v1 && c < c1)) { v2 = v1; c2 = c1; v1 = d; c1 = c; }
                else if (d < v2 || (d == v2 && c < c2)) { v2 = d; c2 = c; }
            }
#pragma unroll
            for (int off = 1; off < 16; off <<= 1) {
                float w1 = __shfl_xor(v1, off); int d1 = __shfl_xor(c1, off);
                float w2 = __shfl_xor(v2, off); int d2 = __shfl_xor(c2, off);
                if (w1 < v1 || (w1 == v1 && d1 < c1)) { v2 = v1; c2 = c1; v1 = w1; c1 = d1; }
                else if (w1 < v2 || (w1 == v2 && d1 < c2)) { v2 = w1; c2 = d1; }
                if (w2 < v2 || (w2 == v2 && d2 < c2)) {
                    if (w2 < v1 || (w2 == v1 && d2 < c1)) { v2 = v1; c2 = c1; v1 = w2; c1 = d2; }
                    else { v2 = w2; c2 = d2; }
                }
            }
            if (frow == 0) red[rloc * 2 + wc] = make_float4(v1, (float)c1, v2, (float)c2);
        }
    }
    __syncthreads();
    if (tid < 128) {
        float4 a = red[tid * 2 + 0];
        float4 b = red[tid * 2 + 1];
        float v1 = a.x, c1 = a.y, v2 = a.z, c2 = a.w;
        if (b.x < v1 || (b.x == v1 && b.y < c1)) { v2 = v1; c2 = c1; v1 = b.x; c1 = b.y; }
        else if (b.x < v2 || (b.x == v2 && b.y < c2)) { v2 = b.x; c2 = b.y; }
        if (b.z < v2 || (b.z == v2 && b.w < c2)) {
            if (b.z < v1 || (b.z == v1 && b.w < c1)) { v2 = v1; c2 = c1; v1 = b.z; c1 = b.w; }
            else { v2 = b.z; c2 = b.w; }
        }
        partials[(size_t)(bm * 128 + tid) * 8 + bn] = make_float4(v1, c1, v2, c2);
    }
}

// ---------------- merge 8 block top-2s -> k, list ambiguous rows ----------------
__global__ __launch_bounds__(256) void finish1_k(const float4* __restrict__ partials,
                                                 float* __restrict__ out_k,
                                                 int* __restrict__ refine_cnt,
                                                 int* __restrict__ refine_list) {
    int r = blockIdx.x * 256 + threadIdx.x;
    float v1 = 3.4e38f, c1 = 2.0e9f, v2 = 3.4e38f, c2 = 2.0e9f;
#pragma unroll
    for (int i = 0; i < 8; ++i) {
        float4 p = partials[(size_t)r * 8 + i];
        if (p.x < v1 || (p.x == v1 && p.y < c1)) { v2 = v1; c2 = c1; v1 = p.x; c1 = p.y; }
        else if (p.x < v2 || (p.x == v2 && p.y < c2)) { v2 = p.x; c2 = p.y; }
        if (p.z < v2 || (p.z == v2 && p.w < c2)) {
            if (p.z < v1 || (p.z == v1 && p.w < c1)) { v2 = v1; c2 = c1; v1 = p.z; c1 = p.w; }
            else { v2 = p.z; c2 = p.w; }
        }
    }
    out_k[r] = c1;
    if (v2 - v1 < EPSGAP) {
        int slot = atomicAdd(refine_cnt, 1);
        refine_list[slot] = r;
    }
}

__global__ void zero_k(int* p) { *p = 0; }

// ---------------- exact f32 re-argmin for near-tie rows (8-row batches) ----------------
__global__ __launch_bounds__(256) void refine_k(const float* __restrict__ ze,
                                                const float* __restrict__ cb,
                                                const float* __restrict__ xn,
                                                const float* __restrict__ yn,
                                                const int* __restrict__ refine_cnt,
                                                const int* __restrict__ refine_list,
                                                float* __restrict__ out_k) {
    __shared__ float zs[RB][ZD];
    __shared__ float rvs[RB][4];
    __shared__ int   rcs[RB][4];
    const int n   = *refine_cnt;
    const int tid = threadIdx.x;
    const int lane = tid & 63, w = tid >> 6;

    for (int base = blockIdx.x * RB; base < n; base += gridDim.x * RB) {
        int nb = n - base; if (nb > RB) nb = RB;
        __syncthreads();
        {   // stage nb z-rows: 32 threads per row, 2 float4 each
            int rr = tid >> 5, p = tid & 31;
            if (rr < nb) {
                int r = refine_list[base + rr];
                const float4* zp = (const float4*)(ze + (size_t)r * ZD);
                ((float4*)zs[rr])[p]      = zp[p];
                ((float4*)zs[rr])[p + 32] = zp[p + 32];
            }
        }
        __syncthreads();

        // dots: thread owns nodes j = tid + m*256 (m=0..3), all RB rows at once
        float dot[RB][4];
#pragma unroll
        for (int rr = 0; rr < RB; ++rr)
#pragma unroll
            for (int m = 0; m < 4; ++m) dot[rr][m] = 0.0f;

        for (int k4 = 0; k4 < 64; ++k4) {
            float4 c[4];
#pragma unroll
            for (int m = 0; m < 4; ++m)
                c[m] = *(const float4*)(cb + (size_t)(tid + m * 256) * ZD + k4 * 4);
#pragma unroll
            for (int rr = 0; rr < RB; ++rr) {
                float4 zv = ((const float4*)zs[rr])[k4];
#pragma unroll
                for (int m = 0; m < 4; ++m) {
                    float d = dot[rr][m];
                    d = fmaf(zv.x, c[m].x, d);
                    d = fmaf(zv.y, c[m].y, d);
                    d = fmaf(zv.z, c[m].z, d);
                    d = fmaf(zv.w, c[m].w, d);
                    dot[rr][m] = d;
                }
            }
        }

        float ynv[4];
#pragma unroll
        for (int m = 0; m < 4; ++m) ynv[m] = yn[tid + m * 256];

        for (int rr = 0; rr < nb; ++rr) {
            int r = refine_list[base + rr];
            float xv = xn[r];
            float bv = 3.4e38f; int bc = 1 << 30;
#pragma unroll
            for (int m = 0; m < 4; ++m) {
                int j = tid + m * 256;
                float d = fmaxf((xv + ynv[m]) - 2.0f * dot[rr][m], 0.0f);
                if (d < bv) { bv = d; bc = j; }   // m ascending -> j ascending
            }
#pragma unroll
            for (int off = 32; off; off >>= 1) {
                float ov = __shfl_down(bv, off);
                int   oc = __shfl_down(bc, off);
                if (ov < bv || (ov == bv && oc < bc)) { bv = ov; bc = oc; }
            }
            if (lane == 0) { rvs[rr][w] = bv; rcs[rr][w] = bc; }
        }
        __syncthreads();
        if (tid < nb) {
            float fv = rvs[tid][0]; int fc = rcs[tid][0];
#pragma unroll
            for (int i = 1; i < 4; ++i)
                if (rvs[tid][i] < fv || (rvs[tid][i] == fv && rcs[tid][i] < fc)) { fv = rvs[tid][i]; fc = rcs[tid][i]; }
            out_k[refine_list[base + tid]] = (float)fc;
        }
    }
}

// ---------------- z_e copy + z_q gather + neighbour weights ----------------
__global__ __launch_bounds__(256) void finish2_k(const float* __restrict__ ze,
                                                 const float* __restrict__ cb,
                                                 const int* __restrict__ epoch_p,
                                                 const float* __restrict__ kf,
                                                 float* __restrict__ out_ze,
                                                 float* __restrict__ out_zq,
                                                 float* __restrict__ out_nw) {
    int row  = blockIdx.x * 4 + (threadIdx.x >> 6);
    int lane = threadIdx.x & 63;

    int ep = epoch_p[0];
    double sig = 16.0 * exp((double)ep * -0.034657359027997265);
    float ninv = (float)(-1.0 / (2.0 * sig * sig));

    int k = (int)kf[row];

    const float4* cbp = (const float4*)(cb + (size_t)k * ZD);
    const float4* zep = (const float4*)(ze + (size_t)row * ZD);
    ((float4*)(out_zq + (size_t)row * ZD))[lane] = cbp[lane];
    ((float4*)(out_ze + (size_t)row * ZD))[lane] = zep[lane];

    int kx = k >> 5, ky = k & 31;
    float4* nwp = (float4*)(out_nw + (size_t)row * NODES);
#pragma unroll
    for (int i = 0; i < 4; ++i) {
        int q = i * 64 + lane;
        int n = q * 4;
        float4 w;
        { int dx = ((n + 0) >> 5) - ky, dy = ((n + 0) & 31) - kx; w.x = __expf((float)(dx * dx + dy * dy) * ninv); }
        { int dx = ((n + 1) >> 5) - ky, dy = ((n + 1) & 31) - kx; w.y = __expf((float)(dx * dx + dy * dy) * ninv); }
        { int dx = ((n + 2) >> 5) - ky, dy = ((n + 2) & 31) - kx; w.z = __expf((float)(dx * dx + dy * dy) * ninv); }
        { int dx = ((n + 3) >> 5) - ky, dy = ((n + 3) & 31) - kx; w.w = __expf((float)(dx * dx + dy * dy) * ninv); }
        nwp[q] = w;
    }
}

extern "C" void kernel_launch(void* const* d_in, const int* in_sizes, int n_in,
                              void* d_out, int out_size, void* d_ws, size_t ws_size,
                              hipStream_t stream) {
    const float* z_e      = (const float*)d_in[0];
    const float* codebook = (const float*)d_in[1];
    const int*   epoch_p  = (const int*)d_in[2];
    float* out = (float*)d_out;

    // scratch in d_out regions that are overwritten later (all stream-ordered):
    //  nw region: Ap, Bp, xn, yn       (finish2 writes nw last)
    //  z_e region: partials            (finish2 writes z_e last)
    //  z_q region: refine count + list (finish2 writes z_q last)
    float* nwreg = out + OFF_NW;
    ushort* Ap = (ushort*)nwreg;                       // [65536][768] bf16
    ushort* Bp = Ap + (size_t)BATCH * KS;              // [1024][768]
    float*  xn = (float*)(Bp + (size_t)NODES * KS);    // [65536]
    float*  yn = xn + BATCH;                           // [1024]
    float4* partials = (float4*)(out + OFF_ZE);        // [65536][8]
    int* refine_cnt  = (int*)(out + OFF_ZQ);           // [1]
    int* refine_list = refine_cnt + 1;                 // [65536]

    zero_k<<<1, 1, 0, stream>>>(refine_cnt);
    split_k<<<BATCH / 4, 256, 0, stream>>>(z_e, Ap, xn, 1);
    split_k<<<NODES / 4, 256, 0, stream>>>(codebook, Bp, yn, 0);

    dist_mfma_k<<<4096, 256, 0, stream>>>(Ap, Bp, xn, yn, out + OFF_DIST, partials);

    finish1_k<<<BATCH / 256, 256, 0, stream>>>(partials, out + OFF_K, refine_cnt, refine_list);
    refine_k<<<512, 256, 0, stream>>>(z_e, codebook, xn, yn, refine_cnt, refine_list, out + OFF_K);
    finish2_k<<<BATCH / 4, 256, 0, stream>>>(z_e, codebook, epoch_p, out + OFF_K,
                                             out + OFF_ZE, out + OFF_ZQ, out + OFF_NW);
}